// Round 3
// baseline (759.422 us; speedup 1.0000x reference)
//
#include <hip/hip_runtime.h>
#include <math.h>

#define B_TOT 16384
#define NPART 16
#define NPAIR 120   // 16*15/2
#define HID   64
#define DL    5

// tanh-approx GELU using hardware exp (v_exp_f32). Max abs deviation from
// exact erf-GELU ~1e-3, vastly below the 0.79 output threshold after the
// 0.01-std readout. Robust at +/-inf ranges of the preactivation.
__device__ __forceinline__ float gelu_fast(float v) {
    float u = 0.7978845608028654f * v * (1.0f + 0.044715f * v * v);
    float e = __expf(2.0f * u);                       // exp(2u)
    float t = 1.0f - 2.0f * __builtin_amdgcn_rcpf(e + 1.0f);  // tanh(u)
    return 0.5f * v * (1.0f + t);
}

// Single fused kernel: block per batch element b, 192 threads (3 waves).
//   wave 0+1 (t in [0,128)): psi pair-MLP, pairs 0..119 active
//   wave 2   (t in [128,192)): phi row-MLP, rows 0..15 active
//   then LDS reduce; wave 0 computes rho readout -> out[b].
// No global workspace (d_ws untouched).
__global__ __launch_bounds__(192) void jastrow_fused(
    const float* __restrict__ x,
    const float* __restrict__ phi_w0, const float* __restrict__ phi_b0,
    const float* __restrict__ phi_w1, const float* __restrict__ phi_b1,
    const float* __restrict__ phi_w2, const float* __restrict__ phi_b2,
    const float* __restrict__ psi_w0, const float* __restrict__ psi_b0,
    const float* __restrict__ psi_w1, const float* __restrict__ psi_b1,
    const float* __restrict__ psi_w2, const float* __restrict__ psi_b2,
    const float* __restrict__ rho_w0, const float* __restrict__ rho_b0,
    const float* __restrict__ rho_w1, const float* __restrict__ rho_b1,
    float* __restrict__ out)
{
    int b = blockIdx.x;
    int t = threadIdx.x;
    int wv = t >> 6;          // 0,1,2
    int lane = t & 63;

    __shared__ float s_w[3][6];   // per-wave partials: [wave][5 outputs + cusp]

    float vals[6] = {0.f, 0.f, 0.f, 0.f, 0.f, 0.f};

    const float2* x2 = (const float2*)x;

    if (t < 128) {
        // ---------------- psi branch: one pair per thread ----------------
        if (t < NPAIR) {
            int i = 0, rem = t;
            while (rem >= NPART - 1 - i) { rem -= NPART - 1 - i; ++i; }
            int j = i + 1 + rem;

            float2 xi = x2[b * NPART + i];
            float2 xj = x2[b * NPART + j];
            float dx = xi.x - xj.x;
            float dy = xi.y - xj.y;
            float r = sqrtf(dx * dx + dy * dy + 1e-12f);

            float f0 = log1pf(r);
            float f1 = r * __builtin_amdgcn_rcpf(1.f + r);
            float f2 = __expf(-r * r);
            float f3 = __expf(-0.5f * r);
            float f4 = __expf(-r);
            float f5 = f4 * f4;          // exp(-2r)
            vals[5] = r * f4;            // cusp term (CUSP_GAMMA = 1)

            float h1[HID];
#pragma unroll
            for (int jj = 0; jj < HID; ++jj) {
                const float* wr = psi_w0 + jj * 6;
                float a = psi_b0[jj] + f0 * wr[0] + f1 * wr[1] + f2 * wr[2]
                                     + f3 * wr[3] + f4 * wr[4] + f5 * wr[5];
                h1[jj] = gelu_fast(a);
            }
            float h2[HID];
#pragma unroll
            for (int jj = 0; jj < HID; ++jj) {
                float a = psi_b1[jj];
#pragma unroll
                for (int k = 0; k < HID; ++k) a += h1[k] * psi_w1[jj * HID + k];
                h2[jj] = gelu_fast(a);
            }
#pragma unroll
            for (int d = 0; d < DL; ++d) {
                float a = psi_b2[d];
#pragma unroll
                for (int k = 0; k < HID; ++k) a += h2[k] * psi_w2[d * HID + k];
                vals[d] = a;
            }
        }
    } else {
        // ---------------- phi branch: one row per thread (16 active) ----------------
        int n = lane;
        if (n < NPART) {
            float2 xv = x2[b * NPART + n];
            float x0 = xv.x, x1 = xv.y;       // OMEGA = 1 -> xs = x
            float r2 = x0 * x0 + x1 * x1;

            float h1[HID];
#pragma unroll
            for (int jj = 0; jj < HID; ++jj) {
                const float* wr = phi_w0 + jj * 3;
                float a = phi_b0[jj] + x0 * wr[0] + x1 * wr[1] + r2 * wr[2];
                h1[jj] = gelu_fast(a);
            }
            float h2[HID];
#pragma unroll
            for (int jj = 0; jj < HID; ++jj) {
                float a = phi_b1[jj];
#pragma unroll
                for (int k = 0; k < HID; ++k) a += h1[k] * phi_w1[jj * HID + k];
                h2[jj] = gelu_fast(a);
            }
#pragma unroll
            for (int d = 0; d < DL; ++d) {
                float a = phi_b2[d];
#pragma unroll
                for (int k = 0; k < HID; ++k) a += h2[k] * phi_w2[d * HID + k];
                vals[d] = a;
            }
        }
    }

    // per-wave reduction (64 lanes) of 6 values
#pragma unroll
    for (int d = 0; d < 6; ++d) {
        float v = vals[d];
        v += __shfl_down(v, 32);
        v += __shfl_down(v, 16);
        v += __shfl_down(v, 8);
        v += __shfl_down(v, 4);
        v += __shfl_down(v, 2);
        v += __shfl_down(v, 1);
        if (lane == 0) s_w[wv][d] = v;
    }
    __syncthreads();

    // ---------------- rho readout on wave 0 ----------------
    if (t < 64) {
        float psiv[DL], phiv[DL];
#pragma unroll
        for (int d = 0; d < DL; ++d) {
            psiv[d] = (s_w[0][d] + s_w[1][d]) * (1.0f / NPAIR);
            phiv[d] = s_w[2][d] * (1.0f / NPART);
        }
        float cusp = s_w[0][5] + s_w[1][5];

        int j = t;   // hidden unit
        float a = rho_b0[j];
        const float* wr = rho_w0 + j * (2 * DL);
#pragma unroll
        for (int k = 0; k < DL; ++k) a += phiv[k] * wr[k];
#pragma unroll
        for (int k = 0; k < DL; ++k) a += psiv[k] * wr[DL + k];
        float c = gelu_fast(a) * rho_w1[j];

        c += __shfl_down(c, 32);
        c += __shfl_down(c, 16);
        c += __shfl_down(c, 8);
        c += __shfl_down(c, 4);
        c += __shfl_down(c, 2);
        c += __shfl_down(c, 1);
        if (t == 0) out[b] = c + rho_b1[0] + cusp;
    }
}

extern "C" void kernel_launch(void* const* d_in, const int* in_sizes, int n_in,
                              void* d_out, int out_size, void* d_ws, size_t ws_size,
                              hipStream_t stream) {
    const float* x      = (const float*)d_in[0];
    const float* phi_w0 = (const float*)d_in[1];
    const float* phi_b0 = (const float*)d_in[2];
    const float* phi_w1 = (const float*)d_in[3];
    const float* phi_b1 = (const float*)d_in[4];
    const float* phi_w2 = (const float*)d_in[5];
    const float* phi_b2 = (const float*)d_in[6];
    const float* psi_w0 = (const float*)d_in[7];
    const float* psi_b0 = (const float*)d_in[8];
    const float* psi_w1 = (const float*)d_in[9];
    const float* psi_b1 = (const float*)d_in[10];
    const float* psi_w2 = (const float*)d_in[11];
    const float* psi_b2 = (const float*)d_in[12];
    const float* rho_w0 = (const float*)d_in[13];
    const float* rho_b0 = (const float*)d_in[14];
    const float* rho_w1 = (const float*)d_in[15];
    const float* rho_b1 = (const float*)d_in[16];

    jastrow_fused<<<B_TOT, 192, 0, stream>>>(
        x,
        phi_w0, phi_b0, phi_w1, phi_b1, phi_w2, phi_b2,
        psi_w0, psi_b0, psi_w1, psi_b1, psi_w2, psi_b2,
        rho_w0, rho_b0, rho_w1, rho_b1,
        (float*)d_out);
}

// Round 4
// 293.376 us; speedup vs baseline: 2.5886x; 2.5886x over previous
//
#include <hip/hip_runtime.h>
#include <math.h>

#define B_TOT 16384
#define NPART 16
#define NPAIR 120     // 16*15/2
#define HID   64
#define DL    5
#define GB    2       // batch elements per block
#define STRIDE 72     // ushorts per LDS row (64 + 8 pad) = 144 B, 16B-aligned
#define PHI_BASE (GB * 128)   // row index where phi rows start (256)

typedef __attribute__((ext_vector_type(8))) short short8;
typedef __attribute__((ext_vector_type(4))) float floatx4;

__device__ __forceinline__ float gelu_fast(float v) {
    float u = 0.7978845608028654f * v * (1.0f + 0.044715f * v * v);
    float e = __expf(2.0f * u);
    float t = 1.0f - 2.0f * __builtin_amdgcn_rcpf(e + 1.0f);   // tanh(u)
    return 0.5f * v * (1.0f + t);
}

__device__ __forceinline__ unsigned short f2bf(float f) {
    union { float f; unsigned u; } v; v.f = f;
    unsigned r = v.u + 0x7fffu + ((v.u >> 16) & 1u);   // RNE
    return (unsigned short)(r >> 16);
}
__device__ __forceinline__ float bf2f(unsigned short s) {
    union { unsigned u; float f; } v; v.u = ((unsigned)s) << 16;
    return v.f;
}

// One block = GB(2) batch elements, 256 threads (4 waves).
// LDS h-buffer rows: [0,256): psi rows (b_local*128 + pair, pairs 120..127 zero-pad)
//                    [256,288): phi rows (b_local*16 + n)
__global__ __launch_bounds__(256) void jastrow_mfma(
    const float* __restrict__ x,
    const float* __restrict__ phi_w0, const float* __restrict__ phi_b0,
    const float* __restrict__ phi_w1, const float* __restrict__ phi_b1,
    const float* __restrict__ phi_w2, const float* __restrict__ phi_b2,
    const float* __restrict__ psi_w0, const float* __restrict__ psi_b0,
    const float* __restrict__ psi_w1, const float* __restrict__ psi_b1,
    const float* __restrict__ psi_w2, const float* __restrict__ psi_b2,
    const float* __restrict__ rho_w0, const float* __restrict__ rho_b0,
    const float* __restrict__ rho_w1, const float* __restrict__ rho_b1,
    float* __restrict__ out)
{
    const int t    = threadIdx.x;
    const int lane = t & 63;
    const int wv   = t >> 6;
    const int bg   = blockIdx.x * GB;          // global batch base

    __shared__ __align__(16) unsigned short s_h[(GB * 128 + GB * NPART) * STRIDE];
    __shared__ float s_psi_red[4][8];          // per-wave psi partials [wv][0..4]+cusp[5]
    __shared__ float s_phi_red[GB][8];         // phi sums per local batch

    const float2* x2 = (const float2*)x;

    float cusp = 0.f;

    // ================= Phase 1: features + layer 1 -> h1 (bf16) in LDS ==========
    {
        const int bl = t >> 7;        // local batch 0/1
        const int p  = t & 127;       // pair slot
        const int rowbase = (bl * 128 + p) * STRIDE;
        if (p < NPAIR) {
            // decode triu pair (i<j)
            int i = 0, rem = p;
            while (rem >= NPART - 1 - i) { rem -= NPART - 1 - i; ++i; }
            int j = i + 1 + rem;
            float2 xi = x2[(bg + bl) * NPART + i];
            float2 xj = x2[(bg + bl) * NPART + j];
            float dx = xi.x - xj.x, dy = xi.y - xj.y;
            float r = sqrtf(dx * dx + dy * dy + 1e-12f);

            float f0 = __logf(1.f + r);
            float f1 = r * __builtin_amdgcn_rcpf(1.f + r);
            float f2 = __expf(-r * r);
            float f3 = __expf(-0.5f * r);
            float f4 = __expf(-r);
            float f5 = f4 * f4;
            cusp = r * f4;            // CUSP_GAMMA = 1, exact fp32

#pragma unroll
            for (int ch = 0; ch < 8; ++ch) {
                short8 v;
#pragma unroll
                for (int e = 0; e < 8; ++e) {
                    int jj = ch * 8 + e;
                    const float* wr = psi_w0 + jj * 6;
                    float a = psi_b0[jj] + f0 * wr[0] + f1 * wr[1] + f2 * wr[2]
                                         + f3 * wr[3] + f4 * wr[4] + f5 * wr[5];
                    v[e] = (short)f2bf(gelu_fast(a));
                }
                *(short8*)&s_h[rowbase + ch * 8] = v;
            }
        } else {
            // zero-pad rows 120..127
            short8 z = (short8)0;
#pragma unroll
            for (int ch = 0; ch < 8; ++ch) *(short8*)&s_h[rowbase + ch * 8] = z;
        }

        // phi layer-1: threads 0..63, each does half a row (32 hidden units)
        if (t < 64) {
            int prow = t >> 1;                 // 0..31
            int bl2 = prow >> 4, n = prow & 15;
            int c0 = (t & 1) * 32;
            float2 xv = x2[(bg + bl2) * NPART + n];
            float x0 = xv.x, x1 = xv.y;
            float r2 = x0 * x0 + x1 * x1;
            int pb = (PHI_BASE + prow) * STRIDE + c0;
#pragma unroll
            for (int ch = 0; ch < 4; ++ch) {
                short8 v;
#pragma unroll
                for (int e = 0; e < 8; ++e) {
                    int jj = c0 + ch * 8 + e;
                    const float* wr = phi_w0 + jj * 3;
                    float a = phi_b0[jj] + x0 * wr[0] + x1 * wr[1] + r2 * wr[2];
                    v[e] = (short)f2bf(gelu_fast(a));
                }
                *(short8*)&s_h[pb + ch * 8] = v;
            }
        }
    }
    __syncthreads();

    // ================= Phase 2: layer 2 via MFMA 16x16x32 bf16 ==================
    // wave wv handles N-tile nt = wv (output cols nt*16 .. nt*16+15)
    const int m15 = lane & 15;
    const int q   = lane >> 4;
    const int colb = wv * 16 + m15;            // this lane's output column

    // B fragments: B[n=lane&15][k=quad*8+j] ; source w1[n][k] (row-major [64][64])
    short8 Bpsi[2], Bphi[2];
#pragma unroll
    for (int Kc = 0; Kc < 2; ++Kc) {
        int k0 = Kc * 32 + q * 8;
        const float* wp = psi_w1 + colb * HID + k0;
        const float* wf = phi_w1 + colb * HID + k0;
        short8 bp, bf;
#pragma unroll
        for (int e = 0; e < 8; ++e) {
            bp[e] = (short)f2bf(wp[e]);
            bf[e] = (short)f2bf(wf[e]);
        }
        Bpsi[Kc] = bp; Bphi[Kc] = bf;
    }

    floatx4 accP[GB][8];
    floatx4 accF[2];
#pragma unroll
    for (int bl = 0; bl < GB; ++bl)
#pragma unroll
        for (int Mt = 0; Mt < 8; ++Mt) accP[bl][Mt] = (floatx4)0.f;
#pragma unroll
    for (int Mt = 0; Mt < 2; ++Mt) accF[Mt] = (floatx4)0.f;

#pragma unroll
    for (int bl = 0; bl < GB; ++bl) {
#pragma unroll
        for (int Mt = 0; Mt < 8; ++Mt) {
            int ab = (bl * 128 + Mt * 16 + m15) * STRIDE + q * 8;
            short8 a0 = *(const short8*)&s_h[ab];
            short8 a1 = *(const short8*)&s_h[ab + 32];
            accP[bl][Mt] = __builtin_amdgcn_mfma_f32_16x16x32_bf16(a0, Bpsi[0], accP[bl][Mt], 0, 0, 0);
            accP[bl][Mt] = __builtin_amdgcn_mfma_f32_16x16x32_bf16(a1, Bpsi[1], accP[bl][Mt], 0, 0, 0);
        }
    }
#pragma unroll
    for (int Mt = 0; Mt < 2; ++Mt) {
        int ab = (PHI_BASE + Mt * 16 + m15) * STRIDE + q * 8;
        short8 a0 = *(const short8*)&s_h[ab];
        short8 a1 = *(const short8*)&s_h[ab + 32];
        accF[Mt] = __builtin_amdgcn_mfma_f32_16x16x32_bf16(a0, Bphi[0], accF[Mt], 0, 0, 0);
        accF[Mt] = __builtin_amdgcn_mfma_f32_16x16x32_bf16(a1, Bphi[1], accF[Mt], 0, 0, 0);
    }
    __syncthreads();   // all A-reads consumed before overwriting with h2

    // ================= Phase 3: bias + gelu, write h2 (bf16) over h1 =============
    {
        float biasP = psi_b1[colb];
        float biasF = phi_b1[colb];
#pragma unroll
        for (int bl = 0; bl < GB; ++bl)
#pragma unroll
            for (int Mt = 0; Mt < 8; ++Mt)
#pragma unroll
                for (int rg = 0; rg < 4; ++rg) {
                    int rowg = bl * 128 + Mt * 16 + q * 4 + rg;   // D row = quad*4+reg
                    float g = gelu_fast(accP[bl][Mt][rg] + biasP);
                    s_h[rowg * STRIDE + colb] = f2bf(g);
                }
#pragma unroll
        for (int Mt = 0; Mt < 2; ++Mt)
#pragma unroll
            for (int rg = 0; rg < 4; ++rg) {
                int rowg = PHI_BASE + Mt * 16 + q * 4 + rg;
                float g = gelu_fast(accF[Mt][rg] + biasF);
                s_h[rowg * STRIDE + colb] = f2bf(g);
            }
    }
    __syncthreads();

    // ================= Phase 4: layer 3 + reductions + rho =======================
    float vals[6] = {0.f, 0.f, 0.f, 0.f, 0.f, 0.f};
    {
        const int bl = t >> 7;
        const int p  = t & 127;
        if (p < NPAIR) {
            int base = (bl * 128 + p) * STRIDE;
            float h2f[HID];
#pragma unroll
            for (int ch = 0; ch < 8; ++ch) {
                short8 c = *(const short8*)&s_h[base + ch * 8];
#pragma unroll
                for (int e = 0; e < 8; ++e) h2f[ch * 8 + e] = bf2f((unsigned short)c[e]);
            }
#pragma unroll
            for (int d = 0; d < DL; ++d) {
                float a = psi_b2[d];
                const float* wr = psi_w2 + d * HID;
#pragma unroll
                for (int k = 0; k < HID; ++k) a += h2f[k] * wr[k];
                vals[d] = a;
            }
            vals[5] = cusp;
        }
    }
    // psi wave reduction (all 4 waves, inactive lanes contribute zeros)
#pragma unroll
    for (int d = 0; d < 6; ++d) {
        float v = vals[d];
        v += __shfl_down(v, 32);
        v += __shfl_down(v, 16);
        v += __shfl_down(v, 8);
        v += __shfl_down(v, 4);
        v += __shfl_down(v, 2);
        v += __shfl_down(v, 1);
        if (lane == 0) s_psi_red[wv][d] = v;
    }

    // phi layer-3: threads 0..31, one row each
    if (t < 32) {
        int base = (PHI_BASE + t) * STRIDE;
        float h2f[HID];
#pragma unroll
        for (int ch = 0; ch < 8; ++ch) {
            short8 c = *(const short8*)&s_h[base + ch * 8];
#pragma unroll
            for (int e = 0; e < 8; ++e) h2f[ch * 8 + e] = bf2f((unsigned short)c[e]);
        }
        float pv[DL];
#pragma unroll
        for (int d = 0; d < DL; ++d) {
            float a = phi_b2[d];
            const float* wr = phi_w2 + d * HID;
#pragma unroll
            for (int k = 0; k < HID; ++k) a += h2f[k] * wr[k];
            pv[d] = a;
        }
        // reduce over 16-lane groups (rows of one local batch)
#pragma unroll
        for (int d = 0; d < DL; ++d) {
            float v = pv[d];
            v += __shfl_down(v, 8, 16);
            v += __shfl_down(v, 4, 16);
            v += __shfl_down(v, 2, 16);
            v += __shfl_down(v, 1, 16);
            if ((t & 15) == 0) s_phi_red[t >> 4][d] = v;
        }
    }
    __syncthreads();

    // rho readout: threads 0..127 (wave w handles local batch w)
    if (t < 128) {
        int blr = t >> 6, j = t & 63;
        float a = rho_b0[j];
        const float* wr = rho_w0 + j * (2 * DL);
#pragma unroll
        for (int d = 0; d < DL; ++d) {
            float phiv = s_phi_red[blr][d] * (1.0f / NPART);
            float psiv = (s_psi_red[2 * blr][d] + s_psi_red[2 * blr + 1][d]) * (1.0f / NPAIR);
            a += phiv * wr[d] + psiv * wr[DL + d];
        }
        float cuspb = s_psi_red[2 * blr][5] + s_psi_red[2 * blr + 1][5];
        float c = gelu_fast(a) * rho_w1[j];
        c += __shfl_down(c, 32);
        c += __shfl_down(c, 16);
        c += __shfl_down(c, 8);
        c += __shfl_down(c, 4);
        c += __shfl_down(c, 2);
        c += __shfl_down(c, 1);
        if (j == 0) out[bg + blr] = c + rho_b1[0] + cuspb;
    }
}

extern "C" void kernel_launch(void* const* d_in, const int* in_sizes, int n_in,
                              void* d_out, int out_size, void* d_ws, size_t ws_size,
                              hipStream_t stream) {
    const float* x      = (const float*)d_in[0];
    const float* phi_w0 = (const float*)d_in[1];
    const float* phi_b0 = (const float*)d_in[2];
    const float* phi_w1 = (const float*)d_in[3];
    const float* phi_b1 = (const float*)d_in[4];
    const float* phi_w2 = (const float*)d_in[5];
    const float* phi_b2 = (const float*)d_in[6];
    const float* psi_w0 = (const float*)d_in[7];
    const float* psi_b0 = (const float*)d_in[8];
    const float* psi_w1 = (const float*)d_in[9];
    const float* psi_b1 = (const float*)d_in[10];
    const float* psi_w2 = (const float*)d_in[11];
    const float* psi_b2 = (const float*)d_in[12];
    const float* rho_w0 = (const float*)d_in[13];
    const float* rho_b0 = (const float*)d_in[14];
    const float* rho_w1 = (const float*)d_in[15];
    const float* rho_b1 = (const float*)d_in[16];

    jastrow_mfma<<<B_TOT / GB, 256, 0, stream>>>(
        x,
        phi_w0, phi_b0, phi_w1, phi_b1, phi_w2, phi_b2,
        psi_w0, psi_b0, psi_w1, psi_b1, psi_w2, psi_b2,
        rho_w0, rho_b0, rho_w1, rho_b1,
        (float*)d_out);
}

// Round 5
// 238.325 us; speedup vs baseline: 3.1865x; 1.2310x over previous
//
#include <hip/hip_runtime.h>
#include <hip/hip_bf16.h>
#include <math.h>

#define B_TOT 16384
#define NPART 16
#define NPAIR 120     // 16*15/2
#define HID   64
#define DL    5
#define GB    2       // batch elements per block
#define STRIDE 72     // ushorts per LDS row (64 + 8 pad) = 144 B, 16B-aligned
#define PHI_BASE (GB * 128)   // 256

typedef __attribute__((ext_vector_type(8))) short short8;
typedef __attribute__((ext_vector_type(4))) float floatx4;

// v * sigmoid(1.702 v): 1 trans exp + 1 rcp. Max abs dev from exact GELU ~0.02,
// far below the 0.79-0.25 error budget (propagates to <0.02 on f).
__device__ __forceinline__ float gelu_sig(float v) {
    float e = __expf(-1.702f * v);
    return v * __builtin_amdgcn_rcpf(1.0f + e);
}

// pack two f32 -> packed bf16 (v_cvt_pk_bf16_f32 on gfx950), a -> low half
__device__ __forceinline__ unsigned pk2(float a, float b) {
    __hip_bfloat162 h = __float22bfloat162_rn(make_float2(a, b));
    union { __hip_bfloat162 h; unsigned u; } cv; cv.h = h;
    return cv.u;
}

__device__ __forceinline__ float wred(float v) {
    v += __shfl_down(v, 32);
    v += __shfl_down(v, 16);
    v += __shfl_down(v, 8);
    v += __shfl_down(v, 4);
    v += __shfl_down(v, 2);
    v += __shfl_down(v, 1);
    return v;
}

// Block = GB(2) batch elements, 256 threads (4 waves).
// LDS h1 rows: [0,256): psi (bl*128+p, pairs 120..127 zero-pad), [256,288): phi.
// Layer-2 via MFMA 16x16x32 bf16; layer-3 folded into column-sums (mean commutes).
__global__ __launch_bounds__(256) void jastrow_mfma2(
    const float* __restrict__ x,
    const float* __restrict__ phi_w0, const float* __restrict__ phi_b0,
    const float* __restrict__ phi_w1, const float* __restrict__ phi_b1,
    const float* __restrict__ phi_w2, const float* __restrict__ phi_b2,
    const float* __restrict__ psi_w0, const float* __restrict__ psi_b0,
    const float* __restrict__ psi_w1, const float* __restrict__ psi_b1,
    const float* __restrict__ psi_w2, const float* __restrict__ psi_b2,
    const float* __restrict__ rho_w0, const float* __restrict__ rho_b0,
    const float* __restrict__ rho_w1, const float* __restrict__ rho_b1,
    float* __restrict__ out)
{
    const int t    = threadIdx.x;
    const int lane = t & 63;
    const int wv   = t >> 6;
    const int bg   = blockIdx.x * GB;

    __shared__ __align__(16) unsigned short s_h[(GB * 128 + GB * NPART) * STRIDE];
    __shared__ float s_red[4][24];   // 21 used: psi[2][5], phi[2][5], cusp

    const float2* x2 = (const float2*)x;
    float cusp = 0.f;

    // ============ Phase 1a: psi features + layer 1 -> h1 bf16 in LDS ============
    {
        const int bl = t >> 7;
        const int p  = t & 127;
        const int rowbase = (bl * 128 + p) * STRIDE;
        if (p < NPAIR) {
            int i = 0, rem = p;
            while (rem >= NPART - 1 - i) { rem -= NPART - 1 - i; ++i; }
            int j = i + 1 + rem;
            float2 xi = x2[(bg + bl) * NPART + i];
            float2 xj = x2[(bg + bl) * NPART + j];
            float dx = xi.x - xj.x, dy = xi.y - xj.y;
            float r = sqrtf(dx * dx + dy * dy + 1e-12f);

            float f0 = __logf(1.f + r);
            float f1 = r * __builtin_amdgcn_rcpf(1.f + r);
            float f2 = __expf(-r * r);
            float f3 = __expf(-0.5f * r);
            float f4 = __expf(-r);
            float f5 = f4 * f4;
            cusp = r * f4;            // exact fp32

#pragma unroll
            for (int ch = 0; ch < 8; ++ch) {
                union { short8 s; unsigned u[4]; } v;
#pragma unroll
                for (int e2 = 0; e2 < 4; ++e2) {
                    int jj = ch * 8 + e2 * 2;
                    const float* w = psi_w0 + jj * 6;
                    float a0 = psi_b0[jj]     + f0 * w[0]  + f1 * w[1]  + f2 * w[2]
                                              + f3 * w[3]  + f4 * w[4]  + f5 * w[5];
                    float a1 = psi_b0[jj + 1] + f0 * w[6]  + f1 * w[7]  + f2 * w[8]
                                              + f3 * w[9]  + f4 * w[10] + f5 * w[11];
                    v.u[e2] = pk2(gelu_sig(a0), gelu_sig(a1));
                }
                *(short8*)&s_h[rowbase + ch * 8] = v.s;
            }
        } else {
            short8 z = (short8)0;
#pragma unroll
            for (int ch = 0; ch < 8; ++ch) *(short8*)&s_h[rowbase + ch * 8] = z;
        }
    }

    // ============ Phase 1b: phi layer 1, 8 units per thread (all 256) ===========
    {
        int prow = t >> 3;            // 0..31  (bl = prow>>4, n = prow&15)
        int seg  = t & 7;             // unit group seg*8 .. +8
        int bl2 = prow >> 4, n = prow & 15;
        float2 xv = x2[(bg + bl2) * NPART + n];
        float r2 = xv.x * xv.x + xv.y * xv.y;
        union { short8 s; unsigned u[4]; } v;
#pragma unroll
        for (int e2 = 0; e2 < 4; ++e2) {
            int jj = seg * 8 + e2 * 2;
            const float* w = phi_w0 + jj * 3;
            float a0 = phi_b0[jj]     + xv.x * w[0] + xv.y * w[1] + r2 * w[2];
            float a1 = phi_b0[jj + 1] + xv.x * w[3] + xv.y * w[4] + r2 * w[5];
            v.u[e2] = pk2(gelu_sig(a0), gelu_sig(a1));
        }
        *(short8*)&s_h[(PHI_BASE + prow) * STRIDE + seg * 8] = v.s;
    }
    __syncthreads();

    // ============ Phase 2: layer 2 via MFMA 16x16x32 bf16 ======================
    const int m15  = lane & 15;
    const int q    = lane >> 4;
    const int colb = wv * 16 + m15;        // this lane's output column

    short8 Bpsi[2], Bphi[2];
#pragma unroll
    for (int Kc = 0; Kc < 2; ++Kc) {
        int k0 = Kc * 32 + q * 8;
        const float* wp = psi_w1 + colb * HID + k0;
        const float* wf = phi_w1 + colb * HID + k0;
        union { short8 s; unsigned u[4]; } bp, bf;
#pragma unroll
        for (int e2 = 0; e2 < 4; ++e2) {
            bp.u[e2] = pk2(wp[e2 * 2], wp[e2 * 2 + 1]);
            bf.u[e2] = pk2(wf[e2 * 2], wf[e2 * 2 + 1]);
        }
        Bpsi[Kc] = bp.s; Bphi[Kc] = bf.s;
    }

    floatx4 accP[GB][8];
    floatx4 accF[2];
#pragma unroll
    for (int bl = 0; bl < GB; ++bl)
#pragma unroll
        for (int Mt = 0; Mt < 8; ++Mt) accP[bl][Mt] = (floatx4)0.f;
#pragma unroll
    for (int Mt = 0; Mt < 2; ++Mt) accF[Mt] = (floatx4)0.f;

#pragma unroll
    for (int bl = 0; bl < GB; ++bl)
#pragma unroll
        for (int Mt = 0; Mt < 8; ++Mt) {
            int ab = (bl * 128 + Mt * 16 + m15) * STRIDE + q * 8;
            short8 a0 = *(const short8*)&s_h[ab];
            short8 a1 = *(const short8*)&s_h[ab + 32];
            accP[bl][Mt] = __builtin_amdgcn_mfma_f32_16x16x32_bf16(a0, Bpsi[0], accP[bl][Mt], 0, 0, 0);
            accP[bl][Mt] = __builtin_amdgcn_mfma_f32_16x16x32_bf16(a1, Bpsi[1], accP[bl][Mt], 0, 0, 0);
        }
#pragma unroll
    for (int Mt = 0; Mt < 2; ++Mt) {       // Mt == local batch (16 rows each)
        int ab = (PHI_BASE + Mt * 16 + m15) * STRIDE + q * 8;
        short8 a0 = *(const short8*)&s_h[ab];
        short8 a1 = *(const short8*)&s_h[ab + 32];
        accF[Mt] = __builtin_amdgcn_mfma_f32_16x16x32_bf16(a0, Bphi[0], accF[Mt], 0, 0, 0);
        accF[Mt] = __builtin_amdgcn_mfma_f32_16x16x32_bf16(a1, Bphi[1], accF[Mt], 0, 0, 0);
    }

    // ============ Phase 3: gelu + in-register column sums (no h2 LDS!) =========
    // D layout: row = q*4+rg, col = colb. psi_out[d] = (1/P) sum_k colsum[k] w2[d,k] + b2[d]
    float red[21];
    {
        float biasP = psi_b1[colb];
        float biasF = phi_b1[colb];
#pragma unroll
        for (int bl = 0; bl < GB; ++bl) {
            float cs = 0.f;
#pragma unroll
            for (int Mt = 0; Mt < 8; ++Mt) {
                if (Mt == 7) {
                    // rows 120..127 are zero-pad (q>=2) -> exclude from colsum
                    if (q < 2) {
#pragma unroll
                        for (int rg = 0; rg < 4; ++rg)
                            cs += gelu_sig(accP[bl][Mt][rg] + biasP);
                    }
                } else {
#pragma unroll
                    for (int rg = 0; rg < 4; ++rg)
                        cs += gelu_sig(accP[bl][Mt][rg] + biasP);
                }
            }
#pragma unroll
            for (int d = 0; d < DL; ++d)
                red[bl * DL + d] = cs * psi_w2[d * HID + colb];
        }
#pragma unroll
        for (int Mt = 0; Mt < 2; ++Mt) {
            float cs = 0.f;
#pragma unroll
            for (int rg = 0; rg < 4; ++rg)
                cs += gelu_sig(accF[Mt][rg] + biasF);
#pragma unroll
            for (int d = 0; d < DL; ++d)
                red[10 + Mt * DL + d] = cs * phi_w2[d * HID + colb];
        }
        red[20] = cusp;
    }

    // per-wave reduction of 21 scalars (partial colsums x weights sum exactly
    // to the full dot product across the 64 lanes)
#pragma unroll
    for (int v = 0; v < 21; ++v) {
        float s = wred(red[v]);
        if (lane == 0) s_red[wv][v] = s;
    }
    __syncthreads();

    // ============ Phase 4: rho readout (threads 0..127, wave per local batch) ===
    if (t < 128) {
        int blr = t >> 6, j = t & 63;
        float a = rho_b0[j];
        const float* wr = rho_w0 + j * (2 * DL);
#pragma unroll
        for (int d = 0; d < DL; ++d) {
            float psiv = (s_red[0][blr * DL + d] + s_red[1][blr * DL + d] +
                          s_red[2][blr * DL + d] + s_red[3][blr * DL + d]) * (1.0f / NPAIR)
                         + psi_b2[d];
            float phiv = (s_red[0][10 + blr * DL + d] + s_red[1][10 + blr * DL + d] +
                          s_red[2][10 + blr * DL + d] + s_red[3][10 + blr * DL + d]) * (1.0f / NPART)
                         + phi_b2[d];
            a += phiv * wr[d] + psiv * wr[DL + d];
        }
        float cuspb = s_red[2 * blr][20] + s_red[2 * blr + 1][20];
        float c = gelu_sig(a) * rho_w1[j];
        c = wred(c);
        if (j == 0) out[bg + blr] = c + rho_b1[0] + cuspb;
    }
}

extern "C" void kernel_launch(void* const* d_in, const int* in_sizes, int n_in,
                              void* d_out, int out_size, void* d_ws, size_t ws_size,
                              hipStream_t stream) {
    const float* x      = (const float*)d_in[0];
    const float* phi_w0 = (const float*)d_in[1];
    const float* phi_b0 = (const float*)d_in[2];
    const float* phi_w1 = (const float*)d_in[3];
    const float* phi_b1 = (const float*)d_in[4];
    const float* phi_w2 = (const float*)d_in[5];
    const float* phi_b2 = (const float*)d_in[6];
    const float* psi_w0 = (const float*)d_in[7];
    const float* psi_b0 = (const float*)d_in[8];
    const float* psi_w1 = (const float*)d_in[9];
    const float* psi_b1 = (const float*)d_in[10];
    const float* psi_w2 = (const float*)d_in[11];
    const float* psi_b2 = (const float*)d_in[12];
    const float* rho_w0 = (const float*)d_in[13];
    const float* rho_b0 = (const float*)d_in[14];
    const float* rho_w1 = (const float*)d_in[15];
    const float* rho_b1 = (const float*)d_in[16];

    jastrow_mfma2<<<B_TOT / GB, 256, 0, stream>>>(
        x,
        phi_w0, phi_b0, phi_w1, phi_b1, phi_w2, phi_b2,
        psi_w0, psi_b0, psi_w1, psi_b1, psi_w2, psi_b2,
        rho_w0, rho_b0, rho_w1, rho_b1,
        (float*)d_out);
}